// Round 11
// baseline (72.920 us; speedup 1.0000x reference)
//
#include <hip/hip_runtime.h>
#include <hip/hip_bf16.h>
#include <math.h>

#define CIN    1024
#define S_TOT  400
#define COUT   255
#define NCH    85
#define NIMG   64
#define NFLAT  (NIMG * S_TOT)   // 25600
#define BN     128               // flat-s tile
#define BK     64
#define NSTEP  16
#define NTHR   512

// LDS: A tile (256 co x 64 k bf16, wOff-swizzled) = 32 KB at 0
//      B tile (128 s  x 64 k bf16, xBoff-swizzled) = 16 KB at 32768
#define BB        32768
#define LDS_BYTES 49152
#define WSTEP_B   32768          // one pre-swizzled W K-step tile

typedef __attribute__((ext_vector_type(8))) short bf16x8;
typedef __attribute__((ext_vector_type(4))) float f32x4;

struct __attribute__((aligned(4))) f4u { float x, y, z, w; };

// A-tile granule (co, kg): row 128B, XOR by co&7 (verified rounds 3-5, 0 conflicts)
__device__ __forceinline__ int wOff(int co, int kg) {
    return (co << 7) + ((kg << 4) ^ ((co & 7) << 4));
}
// B-tile granule (s, kg): row 128B, XOR by (s>>1)&7 — 2-way free on both the
// 4-row staged writes and 16-row fragment reads (verified rounds 3-6)
__device__ __forceinline__ int xBoff(int s, int kg) {
    return BB + (s << 7) + ((kg << 4) ^ (((s >> 1) & 7) << 4));
}

__device__ __forceinline__ unsigned pk2(float a, float b) {
    __hip_bfloat162 h;
    h.x = __float2bfloat16(a);
    h.y = __float2bfloat16(b);
    return *reinterpret_cast<unsigned*>(&h);
}

__device__ __forceinline__ float sigmoidf_(float v) {
    return 1.0f / (1.0f + expf(-v));
}

__device__ __forceinline__ void gload_lds16(const void* g, void* l) {
    __builtin_amdgcn_global_load_lds(
        (const __attribute__((address_space(1))) unsigned int*)g,
        (__attribute__((address_space(3))) unsigned int*)l,
        16, 0, 0);
}

// ---- W pre-pack: fp32 -> bf16 in the exact per-step LDS tile order ----
__global__ __launch_bounds__(256) void w_pre(const float* __restrict__ w,
                                             unsigned short* __restrict__ wbf) {
    int g = blockIdx.x * 256 + threadIdx.x;
    int co    = g >> 7;
    int kgAll = g & 127;
    int k     = kgAll << 3;
    int step  = k >> 6;
    int kg    = (k >> 3) & 7;
    union { unsigned short u[8]; bf16x8 v; } pk;
    if (co < COUT) {
        const float* src = w + (size_t)co * CIN + k;
        #pragma unroll
        for (int j = 0; j < 8; ++j) {
            __hip_bfloat16 h = __float2bfloat16(src[j]);
            pk.u[j] = *reinterpret_cast<unsigned short*>(&h);
        }
    } else {
        #pragma unroll
        for (int j = 0; j < 8; ++j) pk.u[j] = 0;   // pad co=255
    }
    char* dst = reinterpret_cast<char*>(wbf) + step * WSTEP_B + wOff(co, kg);
    *reinterpret_cast<bf16x8*>(dst) = pk.v;
}

// ---- main: 256co x 128s tile, BK=64, m97-style 2-barrier K-loop ----
__global__ __launch_bounds__(NTHR, 2) void yolo_m97(
    const float* __restrict__ xin,
    const unsigned short* __restrict__ wbf,
    const float* __restrict__ bias,
    float* __restrict__ out)
{
    __shared__ __align__(16) char smem[LDS_BYTES];

    const int tile = blockIdx.x * BN;
    const int tid  = threadIdx.x;
    const int lane = tid & 63;
    const int w8   = tid >> 6;        // wave 0..7
    const int llo  = lane & 15;
    const int lhi  = lane >> 4;
    const int co_w = (w8 >> 1) * 64;  // wave co-group (64 co)
    const int s_w  = (w8 & 1) * 64;   // wave s-half (64 s)

    // B staging (tid < 256): bllo sweeps 32 s-quads (128 s), bgrp = ci-octet
    const int bllo = tid & 31;
    const int bgrp = tid >> 5;        // 0..7 for tid<256
    const int flatB = tile + 4 * bllo;
    const int nB = flatB / S_TOT;
    const int sB = flatB - nB * S_TOT;
    const float* xsrcB = xin + ((size_t)nB * CIN + bgrp * 8) * S_TOT + sB;

    f32x4 acc[4][4] = {};

    for (int t = 0; t < NSTEP; ++t) {
        // ---- A: linear gload_lds, 4 x (512 thr x 16B) = 32 KB, 1KB/wave-instr
        const char* wg = (const char*)wbf + (size_t)t * WSTEP_B;
        #pragma unroll
        for (int i = 0; i < 4; ++i)
            gload_lds16(wg + i * 8192 + (size_t)tid * 16,
                        smem + i * 8192 + w8 * 1024);

        // ---- B: 8 x 512B-contiguous float4 rows, reg-transpose, ds_write ----
        if (tid < 256) {
            const float* src = xsrcB + (size_t)t * (BK * S_TOT);
            union F4 { float4 v; float f[4]; } cu[8];
            #pragma unroll
            for (int j = 0; j < 8; ++j) cu[j].v = *(const float4*)(src + j * S_TOT);
            #pragma unroll
            for (int r = 0; r < 4; ++r) {
                union { unsigned u4[4]; bf16x8 b; } rr;
                #pragma unroll
                for (int jj = 0; jj < 4; ++jj)
                    rr.u4[jj] = pk2(cu[2 * jj].f[r], cu[2 * jj + 1].f[r]);
                *(bf16x8*)(smem + xBoff(4 * bllo + r, bgrp)) = rr.b;
            }
        }
        __syncthreads();

        // ---- pure ds_read + MFMA: 16 reads, 32 MFMAs per wave ----
        #pragma unroll
        for (int ks = 0; ks < 2; ++ks) {
            const int kgr = ks * 4 + lhi;
            bf16x8 afr[4], bfr[4];
            #pragma unroll
            for (int mi = 0; mi < 4; ++mi)
                afr[mi] = *(bf16x8*)(smem + wOff(co_w + mi * 16 + llo, kgr));
            #pragma unroll
            for (int ns = 0; ns < 4; ++ns)
                bfr[ns] = *(bf16x8*)(smem + xBoff(s_w + ns * 16 + llo, kgr));
            #pragma unroll
            for (int mi = 0; mi < 4; ++mi)
                #pragma unroll
                for (int ns = 0; ns < 4; ++ns)
                    acc[mi][ns] = __builtin_amdgcn_mfma_f32_16x16x32_bf16(
                        afr[mi], bfr[ns], acc[mi][ns], 0, 0, 0);
        }
        __syncthreads();
    }

    // ---- fused YOLO epilogue: 16B stores of 4 consecutive co ----
    const float anchW[3] = {116.0f, 156.0f, 373.0f};
    const float anchH[3] = {90.0f, 198.0f, 326.0f};

    #pragma unroll
    for (int mi = 0; mi < 4; ++mi) {
        const int co0 = co_w + mi * 16 + lhi * 4;
        const int aW  = co0 / NCH;
        const int c0  = co0 - aW * NCH;
        const bool whole = (c0 <= NCH - 4) && (co0 + 3 < COUT);
        float bv[4];
        #pragma unroll
        for (int r = 0; r < 4; ++r)
            bv[r] = (co0 + r < COUT) ? bias[co0 + r] : 0.0f;

        #pragma unroll
        for (int ns = 0; ns < 4; ++ns) {
            const int flat = tile + s_w + ns * 16 + llo;
            const int n = flat / S_TOT;
            const int s = flat - n * S_TOT;
            const float sx = (float)(s % 20);
            const float sy = (float)(s / 20);
            if (whole) {
                float r4[4];
                #pragma unroll
                for (int r = 0; r < 4; ++r) {
                    const int c = c0 + r;
                    const float v = acc[mi][ns][r] + bv[r];
                    float res;
                    if (c == 0)      res = (sigmoidf_(v) + sx) * 32.0f;
                    else if (c == 1) res = (sigmoidf_(v) + sy) * 32.0f;
                    else if (c == 2) res = expf(v) * anchW[aW];
                    else if (c == 3) res = expf(v) * anchH[aW];
                    else             res = sigmoidf_(v);
                    r4[r] = res;
                }
                f4u* pp = (f4u*)(out + (size_t)n * 102000 + aW * 34000 + s * 85 + c0);
                f4u val = {r4[0], r4[1], r4[2], r4[3]};
                *pp = val;
            } else {
                #pragma unroll
                for (int r = 0; r < 4; ++r) {
                    const int co = co0 + r;
                    if (co < COUT) {
                        const int a2 = co / NCH;
                        const int c  = co - a2 * NCH;
                        const float v = acc[mi][ns][r] + bv[r];
                        float res;
                        if (c == 0)      res = (sigmoidf_(v) + sx) * 32.0f;
                        else if (c == 1) res = (sigmoidf_(v) + sy) * 32.0f;
                        else if (c == 2) res = expf(v) * anchW[a2];
                        else if (c == 3) res = expf(v) * anchH[a2];
                        else             res = sigmoidf_(v);
                        out[(size_t)n * 102000 + a2 * 34000 + s * 85 + c] = res;
                    }
                }
            }
        }
    }
}

extern "C" void kernel_launch(void* const* d_in, const int* in_sizes, int n_in,
                              void* d_out, int out_size, void* d_ws, size_t ws_size,
                              hipStream_t stream) {
    const float* xin  = (const float*)d_in[0];
    const float* w    = (const float*)d_in[1];
    const float* bias = (const float*)d_in[2];
    float* out = (float*)d_out;
    unsigned short* wbf = (unsigned short*)d_ws;   // 512 KiB

    w_pre<<<128, 256, 0, stream>>>(w, wbf);
    yolo_m97<<<NFLAT / BN, NTHR, 0, stream>>>(xin, wbf, bias, out);
}